// Round 5
// baseline (3919.875 us; speedup 1.0000x reference)
//
#include <hip/hip_runtime.h>
#include <hip/hip_bf16.h>

#define NN 100000
#define EE 3200000
#define CC 64
#define NC (NN*CC)
#define SCAN_BLOCKS 391        // ceil(NN/256)
#define ERR_BLOCKS 6250        // NC/4/256

// Chunked layouts (4 chunks x 16 classes):
//   curn  (bf16x2 packed): uint   [4][NN][8]   -> 32 B per node-chunk
//   base  (fp32)         : float  [4][NN][16]  -> 64 B per node-chunk
//   smoothed (fp32)      : same chunked layout as base

// ---------------- helpers ----------------
__device__ __forceinline__ float ldf(const void* p, long i, int isbf) {
    if (isbf) {
        unsigned int u = ((const unsigned short*)p)[i];
        return __uint_as_float(u << 16);
    }
    return ((const float*)p)[i];
}

__device__ __forceinline__ float wave_sum(float a) {
    for (int m = 1; m < 64; m <<= 1) a += __shfl_xor(a, m, 64);
    return a;
}

// round-to-nearest-even bf16 pack of (a -> low16, b -> high16)
__device__ __forceinline__ unsigned pack_bf16(float a, float b) {
    unsigned ua = __float_as_uint(a); ua = (ua + 0x7FFFu + ((ua >> 16) & 1u)) >> 16;
    unsigned ub = __float_as_uint(b); ub = (ub + 0x7FFFu + ((ub >> 16) & 1u)) >> 16;
    return ua | (ub << 16);
}

// ---------------- detection (1 block, sampled) ----------------
__global__ void detect_kernel(const void* ytrue, const void* mask, int* flags) {
    int t = threadIdx.x;
    const unsigned int* w = (const unsigned int*)ytrue;
    int nb = 0, nm = 0;
    for (int i = t; i < 16384; i += 256)
        if ((w[i] & 0xFFFFu) == 0x3F80u) nb = 1;   // bf16 1.0 at even class
    const unsigned char* mb = (const unsigned char*)mask;
    for (int i = t; i < 4096; i += 256)
        if ((i & 3) != 0 && mb[i] != 0) nm = 1;
    if (nb) atomicOr(&flags[0], 1);
    if (nm) atomicOr(&flags[1], 1);
}

// ---------------- prep: wave per node; label via ballot ----------------
__global__ void prep_kernel(const void* ytrue, const void* mask, const int* flags,
                            int* __restrict__ label, float* __restrict__ mask01) {
    int gt = blockIdx.x * blockDim.x + threadIdx.x;
    int node = gt >> 6, lane = gt & 63;
    if (node >= NN) return;
    int isbf = flags[0];
    float tv = ldf(ytrue, (long)node * CC + lane, isbf);
    unsigned long long b = __ballot(tv > 0.5f);
    if (lane == 0) {
        label[node] = (b == 0ull) ? 0 : (__ffsll((long long)b) - 1);
        int mv = flags[1] ? (int)((const unsigned char*)mask)[node] : ((const int*)mask)[node];
        mask01[node] = mv ? 1.f : 0.f;
    }
}

// ---------------- degree ----------------
__global__ void deg_kernel(const int* __restrict__ dst, int* __restrict__ degi) {
    int e = blockIdx.x * blockDim.x + threadIdx.x;
    if (e < EE) atomicAdd(&degi[dst[e]], 1);
}

__global__ void norm_kernel(const int* __restrict__ degi, float* __restrict__ norm) {
    int n = blockIdx.x * blockDim.x + threadIdx.x;
    if (n < NN) {
        int d = degi[n]; if (d < 1) d = 1;
        norm[n] = rsqrtf((float)d);
    }
}

// ---------------- scans ----------------
__global__ void scan1_kernel(const int* __restrict__ degi, int* __restrict__ partials) {
    int t = threadIdx.x, i = blockIdx.x * 256 + t;
    __shared__ int sm[256];
    sm[t] = (i < NN) ? degi[i] : 0; __syncthreads();
    for (int s = 128; s > 0; s >>= 1) {
        if (t < s) sm[t] += sm[t + s];
        __syncthreads();
    }
    if (t == 0) partials[blockIdx.x] = sm[0];
}

__global__ void scan2_kernel(const int* __restrict__ partials, int* __restrict__ chunk_off) {
    int t = threadIdx.x;
    __shared__ int sm[512];
    int v = (t < SCAN_BLOCKS) ? partials[t] : 0;
    sm[t] = v; __syncthreads();
    for (int off = 1; off < 512; off <<= 1) {
        int x = (t >= off) ? sm[t - off] : 0;
        __syncthreads();
        sm[t] += x;
        __syncthreads();
    }
    chunk_off[t] = sm[t] - v;
}

__global__ void scan3_kernel(const int* __restrict__ degi, const int* __restrict__ chunk_off,
                             int* __restrict__ row_ptr, int* __restrict__ cursor) {
    int t = threadIdx.x, b = blockIdx.x, i = b * 256 + t;
    __shared__ int sm[256];
    int v = (i < NN) ? degi[i] : 0;
    sm[t] = v; __syncthreads();
    for (int off = 1; off < 256; off <<= 1) {
        int x = (t >= off) ? sm[t - off] : 0;
        __syncthreads();
        sm[t] += x;
        __syncthreads();
    }
    int base = chunk_off[b];
    if (i < NN) {
        int ex = base + sm[t] - v;
        row_ptr[i] = ex; cursor[i] = ex;
    }
    if (i == NN - 1) row_ptr[NN] = base + sm[t];
}

// ---------------- CSR fill ----------------
__global__ void fill_kernel(const int* __restrict__ src, const int* __restrict__ dst,
                            int* __restrict__ cursor, int* __restrict__ csr_src) {
    int e = blockIdx.x * blockDim.x + threadIdx.x;
    if (e < EE) {
        int pos = atomicAdd(&cursor[dst[e]], 1);
        csr_src[pos] = src[e];
    }
}

// ---------------- initial error: base fp32 (chunked), curn bf16 (chunked) ----------------
__global__ void err_kernel(const void* ysoft, const int* flags, const int* __restrict__ label,
                           const float* __restrict__ mask01, const float* __restrict__ norm,
                           float* __restrict__ base, unsigned* __restrict__ curn,
                           float* __restrict__ err_part) {
    int i4 = blockIdx.x * 256 + threadIdx.x;     // standard float4 index
    int node = i4 >> 4;
    int w16 = i4 & 15;
    int chunk = w16 >> 2, q = w16 & 3;
    long ci = ((long)chunk * NN + node) * 4 + q; // float4 / uint2 index in chunked arrays
    int isbf = flags[0];
    float m = mask01[node];
    int lab = label[node];
    float nrm = norm[node];
    int c0 = w16 * 4;
    float4 e;
    if (isbf) {
        ushort4 u = ((const ushort4*)ysoft)[i4];
        e.x = __uint_as_float((unsigned)u.x << 16);
        e.y = __uint_as_float((unsigned)u.y << 16);
        e.z = __uint_as_float((unsigned)u.z << 16);
        e.w = __uint_as_float((unsigned)u.w << 16);
    } else {
        e = ((const float4*)ysoft)[i4];
    }
    e.x = (m != 0.f) ? ((c0 + 0 == lab) ? 1.f : 0.f) - e.x : 0.f;
    e.y = (m != 0.f) ? ((c0 + 1 == lab) ? 1.f : 0.f) - e.y : 0.f;
    e.z = (m != 0.f) ? ((c0 + 2 == lab) ? 1.f : 0.f) - e.z : 0.f;
    e.w = (m != 0.f) ? ((c0 + 3 == lab) ? 1.f : 0.f) - e.w : 0.f;
    ((float4*)base)[ci] = e;
    ((uint2*)curn)[ci] = make_uint2(pack_bf16(e.x * nrm, e.y * nrm),
                                    pack_bf16(e.z * nrm, e.w * nrm));
    float a = fabsf(e.x) + fabsf(e.y) + fabsf(e.z) + fabsf(e.w);
    a = wave_sum(a);
    __shared__ float sm[4];
    if ((threadIdx.x & 63) == 0) sm[threadIdx.x >> 6] = a;
    __syncthreads();
    if (threadIdx.x == 0) err_part[blockIdx.x] = sm[0] + sm[1] + sm[2] + sm[3];
}

// ---------------- single-block reduce: scal[0]=numel, scal[1]=sum|err| ----------------
__global__ void reduce_kernel(const float* __restrict__ mask01,
                              const float* __restrict__ err_part, float* __restrict__ scal) {
    int t = threadIdx.x;
    float s0 = 0.f, s1 = 0.f;
    for (int i = t; i < NN; i += 1024) s0 += mask01[i];
    for (int i = t; i < ERR_BLOCKS; i += 1024) s1 += err_part[i];
    __shared__ float a0[1024], a1[1024];
    a0[t] = s0; a1[t] = s1; __syncthreads();
    for (int s = 512; s > 0; s >>= 1) {
        if (t < s) { a0[t] += a0[t + s]; a1[t] += a1[t + s]; }
        __syncthreads();
    }
    if (t == 0) { scal[0] = a0[0]; scal[1] = a1[0]; }
}

// ---------------- XCD-chunked pull-gather ----------------
// chunk = blockIdx & 3 -> with round-robin blockIdx->XCD this pins each class-chunk's
// 3.2 MB curn slice to 2 XCDs' L2s. 8 lanes/edge (16 classes), 8 edges per wave-step.
// mode 0: store pack_bf16(v*nrm); mode 1: store fp32 v + atomic rowsum; mode 3: d_out.
__global__ void __launch_bounds__(256)
gather_kernel(const int* __restrict__ row_ptr, const int* __restrict__ csr_src,
              const unsigned* __restrict__ curn, const float* __restrict__ base,
              const float* __restrict__ norm, void* __restrict__ out,
              float* __restrict__ rowsum, const int* flags,
              float alpha, float lo, float hi, int mode) {
    int chunk = blockIdx.x & 3;
    int node = (blockIdx.x >> 2) * 4 + (threadIdx.x >> 6);
    int lane = threadIdx.x & 63;
    int group = lane >> 3, gl = lane & 7;
    long cbase = (long)chunk * NN;
    const unsigned* __restrict__ cw = curn + cbase * 8;
    int beg = row_ptr[node], end = row_ptr[node + 1];
    float acc0 = 0.f, acc1 = 0.f;
    for (int eb = beg; eb < end; eb += 64) {
        int ne = end - eb; if (ne > 64) ne = 64;
        int sv = (eb + lane < end) ? __builtin_nontemporal_load(csr_src + eb + lane) : 0;
        int j = 0;
        for (; j + 31 < ne; j += 32) {
            int s0 = __shfl(sv, j + group, 64);
            int s1 = __shfl(sv, j + 8 + group, 64);
            int s2 = __shfl(sv, j + 16 + group, 64);
            int s3 = __shfl(sv, j + 24 + group, 64);
            unsigned w0 = cw[(long)s0 * 8 + gl];
            unsigned w1 = cw[(long)s1 * 8 + gl];
            unsigned w2 = cw[(long)s2 * 8 + gl];
            unsigned w3 = cw[(long)s3 * 8 + gl];
            acc0 += __uint_as_float(w0 << 16) + __uint_as_float(w1 << 16)
                  + __uint_as_float(w2 << 16) + __uint_as_float(w3 << 16);
            acc1 += __uint_as_float(w0 & 0xFFFF0000u) + __uint_as_float(w1 & 0xFFFF0000u)
                  + __uint_as_float(w2 & 0xFFFF0000u) + __uint_as_float(w3 & 0xFFFF0000u);
        }
        for (; j < ne; j += 8) {
            int ej = j + group;
            int s = __shfl(sv, (ej < ne) ? ej : j, 64);
            float wt = (ej < ne) ? 1.f : 0.f;
            unsigned w = cw[(long)s * 8 + gl];
            acc0 += wt * __uint_as_float(w << 16);
            acc1 += wt * __uint_as_float(w & 0xFFFF0000u);
        }
    }
    // fold 8 edge-groups -> full sums (replicated in every lane)
    acc0 += __shfl_xor(acc0, 8, 64);  acc1 += __shfl_xor(acc1, 8, 64);
    acc0 += __shfl_xor(acc0, 16, 64); acc1 += __shfl_xor(acc1, 16, 64);
    acc0 += __shfl_xor(acc0, 32, 64); acc1 += __shfl_xor(acc1, 32, 64);

    float nrm = norm[node];
    long i2 = (cbase + node) * 8 + gl;   // float2 / uint index in chunked arrays
    float2 b2;
    {   // nontemporal read of base (read-once per layer; don't evict curn from L2)
        const float* bp = base + i2 * 2;
        b2.x = __builtin_nontemporal_load(bp);
        b2.y = __builtin_nontemporal_load(bp + 1);
    }
    float v0 = (1.f - alpha) * b2.x + alpha * nrm * acc0;
    float v1 = (1.f - alpha) * b2.y + alpha * nrm * acc1;
    v0 = v0 < lo ? lo : (v0 > hi ? hi : v0);
    v1 = v1 < lo ? lo : (v1 > hi ? hi : v1);

    if (mode == 0) {
        if (lane < 8) ((unsigned*)out)[i2] = pack_bf16(v0 * nrm, v1 * nrm);
    } else if (mode == 1) {
        float rs = fabsf(v0) + fabsf(v1);
        rs += __shfl_xor(rs, 1, 64); rs += __shfl_xor(rs, 2, 64); rs += __shfl_xor(rs, 4, 64);
        if (lane == 0) atomicAdd(&rowsum[node], rs);
        if (lane < 8) ((float2*)out)[i2] = make_float2(v0, v1);
    } else {
        if (lane < 8) {
            long oi = (long)node * 32 + chunk * 8 + gl;   // standard layout class pair
            if (flags[0]) ((unsigned*)out)[oi] = pack_bf16(v0, v1);
            else          ((float2*)out)[oi] = make_float2(v0, v1);
        }
    }
}

// ---------------- per-node scale ----------------
__global__ void scale_kernel(const float* __restrict__ rowsum, const float* __restrict__ scal,
                             float* __restrict__ scale) {
    int n = blockIdx.x * blockDim.x + threadIdx.x;
    if (n >= NN) return;
    float sigma = scal[1] / scal[0];
    float s = sigma / rowsum[n];
    if (isinf(s) || s > 1000.f) s = 1.f;  // NaN falls through (matches ref)
    scale[n] = s;
}

// ---------------- y0: base=y0 fp32 (chunked), curn=bf16(y0*norm) (chunked) ----------------
__global__ void y0_kernel(const void* ysoft, const int* flags, const int* __restrict__ label,
                          const float* __restrict__ mask01, const float* __restrict__ scale,
                          const float* __restrict__ norm, const float* __restrict__ smoothed,
                          float* __restrict__ base, unsigned* __restrict__ curn) {
    int i4 = blockIdx.x * 256 + threadIdx.x;
    int node = i4 >> 4;
    int w16 = i4 & 15;
    int chunk = w16 >> 2, q = w16 & 3;
    long ci = ((long)chunk * NN + node) * 4 + q;
    int isbf = flags[0];
    float m = mask01[node];
    int lab = label[node];
    float nrm = norm[node], sc = scale[node];
    int c0 = w16 * 4;
    float4 ys;
    if (isbf) {
        ushort4 u = ((const ushort4*)ysoft)[i4];
        ys.x = __uint_as_float((unsigned)u.x << 16);
        ys.y = __uint_as_float((unsigned)u.y << 16);
        ys.z = __uint_as_float((unsigned)u.z << 16);
        ys.w = __uint_as_float((unsigned)u.w << 16);
    } else {
        ys = ((const float4*)ysoft)[i4];
    }
    float4 sm = ((const float4*)smoothed)[ci];
    float rx = ys.x + sc * sm.x; if (isnan(rx)) rx = ys.x;
    float ry = ys.y + sc * sm.y; if (isnan(ry)) ry = ys.y;
    float rz = ys.z + sc * sm.z; if (isnan(rz)) rz = ys.z;
    float rw = ys.w + sc * sm.w; if (isnan(rw)) rw = ys.w;
    float4 y;
    y.x = (m != 0.f) ? ((c0 + 0 == lab) ? 1.f : 0.f) : rx;
    y.y = (m != 0.f) ? ((c0 + 1 == lab) ? 1.f : 0.f) : ry;
    y.z = (m != 0.f) ? ((c0 + 2 == lab) ? 1.f : 0.f) : rz;
    y.w = (m != 0.f) ? ((c0 + 3 == lab) ? 1.f : 0.f) : rw;
    ((float4*)base)[ci] = y;
    ((uint2*)curn)[ci] = make_uint2(pack_bf16(y.x * nrm, y.y * nrm),
                                    pack_bf16(y.z * nrm, y.w * nrm));
}

extern "C" void kernel_launch(void* const* d_in, const int* in_sizes, int n_in,
                              void* d_out, int out_size, void* d_ws, size_t ws_size,
                              hipStream_t stream) {
    const void* ysoft = d_in[0];
    const void* ytrue = d_in[1];
    const int* src = (const int*)d_in[2];
    const int* dst = (const int*)d_in[3];
    const void* mask = d_in[4];

    char* ws = (char*)d_ws;
    // ---- zeroed region ----
    int*   flags     = (int*)ws;
    float* scal      = (float*)(ws + 64);
    int*   partials  = (int*)(ws + 4096);
    int*   chunk_off = (int*)(ws + 8192);
    float* err_part  = (float*)(ws + 12288);           // ERR_BLOCKS floats (25 KB)
    int*   degi      = (int*)(ws + 40960);             // NN ints
    float* rowsum    = (float*)(ws + 40960 + (size_t)NN * 4);  // NN floats (atomic target)
    size_t ZERO_BYTES = 40960 + (size_t)NN * 8;

    size_t off = (ZERO_BYTES + 255) & ~(size_t)255;
    int*   label   = (int*)(ws + off);   off += (size_t)NN * 4;
    float* mask01  = (float*)(ws + off); off += (size_t)NN * 4;
    float* norm    = (float*)(ws + off); off += (size_t)NN * 4;
    float* scale   = (float*)(ws + off); off += (size_t)NN * 4;
    int*   row_ptr = (int*)(ws + off);   off += (size_t)(NN + 1) * 4;
    int*   cursor  = (int*)(ws + off);   off += (size_t)NN * 4;
    off = (off + 255) & ~(size_t)255;
    int*   csr_src  = (int*)(ws + off);      off += (size_t)EE * 4;
    off = (off + 255) & ~(size_t)255;
    float*    base     = (float*)(ws + off);    off += (size_t)NC * 4;   // chunked
    float*    smoothed = (float*)(ws + off);    off += (size_t)NC * 4;   // chunked
    unsigned* bufA     = (unsigned*)(ws + off); off += (size_t)NC * 2;   // chunked bf16
    unsigned* bufB     = (unsigned*)(ws + off); off += (size_t)NC * 2;

    hipMemsetAsync(ws, 0, ZERO_BYTES, stream);

    detect_kernel<<<1, 256, 0, stream>>>(ytrue, mask, flags);
    prep_kernel<<<(NN * 64 + 255) / 256, 256, 0, stream>>>(ytrue, mask, flags, label, mask01);
    deg_kernel<<<(EE + 255) / 256, 256, 0, stream>>>(dst, degi);
    norm_kernel<<<(NN + 255) / 256, 256, 0, stream>>>(degi, norm);
    scan1_kernel<<<SCAN_BLOCKS, 256, 0, stream>>>(degi, partials);
    scan2_kernel<<<1, 512, 0, stream>>>(partials, chunk_off);
    scan3_kernel<<<SCAN_BLOCKS, 256, 0, stream>>>(degi, chunk_off, row_ptr, cursor);
    fill_kernel<<<(EE + 255) / 256, 256, 0, stream>>>(src, dst, cursor, csr_src);
    err_kernel<<<ERR_BLOCKS, 256, 0, stream>>>(ysoft, flags, label, mask01, norm, base, bufA, err_part);
    reduce_kernel<<<1, 1024, 0, stream>>>(mask01, err_part, scal);

    const int gather_blocks = NN;  // 4 chunks x NN/4 node-quads

    // ---- correct phase: 10 layers, alpha=0.979, clip [-1,1]
    unsigned* cur = bufA; unsigned* nxt = bufB;
    for (int l = 0; l < 10; l++) {
        int mode = (l < 9) ? 0 : 1;
        void* o = (l < 9) ? (void*)nxt : (void*)smoothed;
        gather_kernel<<<gather_blocks, 256, 0, stream>>>(row_ptr, csr_src, cur, base, norm, o,
                                                         rowsum, flags, 0.979f, -1.f, 1.f, mode);
        unsigned* t = cur; cur = nxt; nxt = t;
    }

    scale_kernel<<<(NN + 255) / 256, 256, 0, stream>>>(rowsum, scal, scale);
    y0_kernel<<<ERR_BLOCKS, 256, 0, stream>>>(ysoft, flags, label, mask01, scale, norm,
                                              smoothed, base, bufA);

    // ---- smooth phase: 10 layers, alpha=0.756, clip [0,1]; last writes d_out
    cur = bufA; nxt = bufB;
    for (int l = 0; l < 10; l++) {
        int mode = (l < 9) ? 0 : 3;
        void* o = (l < 9) ? (void*)nxt : (void*)d_out;
        gather_kernel<<<gather_blocks, 256, 0, stream>>>(row_ptr, csr_src, cur, base, norm, o,
                                                         rowsum, flags, 0.756f, 0.f, 1.f, mode);
        unsigned* t = cur; cur = nxt; nxt = t;
    }
}

// Round 6
// 1497.622 us; speedup vs baseline: 2.6174x; 2.6174x over previous
//
#include <hip/hip_runtime.h>
#include <hip/hip_bf16.h>

#define NN 100000
#define EE 3200000
#define CC 64
#define NC (NN*CC)
#define ERR_BLOCKS 6250        // NC/4/256
#define NB 391                 // buckets = dst>>8, ceil(NN/256)
#define TILE 8192              // edges per binA block
#define NTILE 391              // ceil(EE/TILE)

// ---------------- helpers ----------------
__device__ __forceinline__ float ldf(const void* p, long i, int isbf) {
    if (isbf) {
        unsigned int u = ((const unsigned short*)p)[i];
        return __uint_as_float(u << 16);
    }
    return ((const float*)p)[i];
}

__device__ __forceinline__ float wave_sum(float a) {
    for (int m = 1; m < 64; m <<= 1) a += __shfl_xor(a, m, 64);
    return a;
}

// round-to-nearest-even bf16 pack of (a -> low16, b -> high16)
__device__ __forceinline__ unsigned pack_bf16(float a, float b) {
    unsigned ua = __float_as_uint(a); ua = (ua + 0x7FFFu + ((ua >> 16) & 1u)) >> 16;
    unsigned ub = __float_as_uint(b); ub = (ub + 0x7FFFu + ((ub >> 16) & 1u)) >> 16;
    return ua | (ub << 16);
}

// ---------------- detection (1 block, sampled) ----------------
__global__ void detect_kernel(const void* ytrue, const void* mask, int* flags) {
    int t = threadIdx.x;
    const unsigned int* w = (const unsigned int*)ytrue;
    int nb = 0, nm = 0;
    for (int i = t; i < 16384; i += 256)
        if ((w[i] & 0xFFFFu) == 0x3F80u) nb = 1;   // bf16 1.0 at even class
    const unsigned char* mb = (const unsigned char*)mask;
    for (int i = t; i < 4096; i += 256)
        if ((i & 3) != 0 && mb[i] != 0) nm = 1;
    if (nb) atomicOr(&flags[0], 1);
    if (nm) atomicOr(&flags[1], 1);
}

// ---------------- prep: wave per node; label via ballot ----------------
__global__ void prep_kernel(const void* ytrue, const void* mask, const int* flags,
                            int* __restrict__ label, float* __restrict__ mask01) {
    int gt = blockIdx.x * blockDim.x + threadIdx.x;
    int node = gt >> 6, lane = gt & 63;
    if (node >= NN) return;
    int isbf = flags[0];
    float tv = ldf(ytrue, (long)node * CC + lane, isbf);
    unsigned long long b = __ballot(tv > 0.5f);
    if (lane == 0) {
        label[node] = (b == 0ull) ? 0 : (__ffsll((long long)b) - 1);
        int mv = flags[1] ? (int)((const unsigned char*)mask)[node] : ((const int*)mask)[node];
        mask01[node] = mv ? 1.f : 0.f;
    }
}

// ---------------- bucket histogram (LDS-aggregated) ----------------
__global__ void histA_kernel(const int* __restrict__ dst, int* __restrict__ bucket_tot) {
    __shared__ int hist[NB];
    int t = threadIdx.x;
    for (int b = t; b < NB; b += 256) hist[b] = 0;
    __syncthreads();
    int e0 = blockIdx.x * TILE;
    int n = EE - e0; if (n > TILE) n = TILE;
    for (int k = t; k < n; k += 256)
        atomicAdd(&hist[dst[e0 + k] >> 8], 1);
    __syncthreads();
    for (int b = t; b < NB; b += 256)
        if (hist[b]) atomicAdd(&bucket_tot[b], hist[b]);
}

// ---------------- scan bucket totals -> bucket_base / bucket_fill ----------------
__global__ void bscan_kernel(const int* __restrict__ bucket_tot,
                             int* __restrict__ bucket_base, int* __restrict__ bucket_fill) {
    int t = threadIdx.x;
    __shared__ int sm[512];
    int v = (t < NB) ? bucket_tot[t] : 0;
    sm[t] = v; __syncthreads();
    for (int off = 1; off < 512; off <<= 1) {
        int x = (t >= off) ? sm[t - off] : 0;
        __syncthreads();
        sm[t] += x;
        __syncthreads();
    }
    int ex = sm[t] - v;
    if (t <= NB) { bucket_base[t] = ex; bucket_fill[t] = ex; }
}

// ---------------- binning: LDS-stage a tile sorted by bucket, write runs ----------------
__global__ void __launch_bounds__(512)
binA_kernel(const int* __restrict__ src, const int* __restrict__ dst,
            int* __restrict__ bucket_fill, uint2* __restrict__ tmp) {
    __shared__ uint2 stage[TILE];
    __shared__ int hist[512], hofs[512], curL[512], gbase[512];
    __shared__ int sm[512];
    int t = threadIdx.x;
    int e0 = blockIdx.x * TILE;
    int n = EE - e0; if (n > TILE) n = TILE;

    hist[t] = 0;
    __syncthreads();
    // local histogram
    for (int k = t; k < n; k += 512)
        atomicAdd(&hist[dst[e0 + k] >> 8], 1);
    __syncthreads();
    // exclusive scan of hist -> hofs
    int v = hist[t];
    sm[t] = v; __syncthreads();
    for (int off = 1; off < 512; off <<= 1) {
        int x = (t >= off) ? sm[t - off] : 0;
        __syncthreads();
        sm[t] += x;
        __syncthreads();
    }
    hofs[t] = sm[t] - v;
    curL[t] = sm[t] - v;
    __syncthreads();
    // stage pairs into LDS grouped by bucket
    for (int k = t; k < n; k += 512) {
        int s = src[e0 + k], d = dst[e0 + k];
        int b = d >> 8;
        int p = atomicAdd(&curL[b], 1);
        stage[p] = make_uint2((unsigned)s, (unsigned)d);
    }
    // reserve global ranges
    if (t < NB) {
        int c = hist[t];
        gbase[t] = c ? atomicAdd(&bucket_fill[t], c) : 0;
    }
    __syncthreads();
    // write runs: sequential LDS scan, contiguous global runs per bucket
    for (int k = t; k < n; k += 512) {
        uint2 pr = stage[k];
        int b = (int)(pr.y >> 8);
        tmp[gbase[b] + (k - hofs[b])] = pr;
    }
}

// ---------------- per-bucket exact counting sort; emits row_ptr, norm, csr_src ----------
__global__ void __launch_bounds__(256)
csrB_kernel(const uint2* __restrict__ tmp, const int* __restrict__ bucket_base,
            int* __restrict__ row_ptr, float* __restrict__ norm, int* __restrict__ csr_src) {
    __shared__ int deg[256], cur[256], sm[256];
    int t = threadIdx.x, b = blockIdx.x;
    int ebeg = bucket_base[b], eend = bucket_base[b + 1];
    deg[t] = 0;
    __syncthreads();
    for (int i = ebeg + t; i < eend; i += 256)
        atomicAdd(&deg[tmp[i].y & 255u], 1);
    __syncthreads();
    int v = deg[t];
    sm[t] = v; __syncthreads();
    for (int off = 1; off < 256; off <<= 1) {
        int x = (t >= off) ? sm[t - off] : 0;
        __syncthreads();
        sm[t] += x;
        __syncthreads();
    }
    int lofs = sm[t] - v;
    int node = b * 256 + t;
    if (node < NN) {
        row_ptr[node] = ebeg + lofs;
        int d = v; if (d < 1) d = 1;
        norm[node] = rsqrtf((float)d);
    }
    if (b == NB - 1 && t == 0) row_ptr[NN] = EE;
    cur[t] = lofs;
    __syncthreads();
    for (int i = ebeg + t; i < eend; i += 256) {
        uint2 pr = tmp[i];
        int p = atomicAdd(&cur[pr.y & 255u], 1);
        csr_src[ebeg + p] = (int)pr.x;
    }
}

// ---------------- initial error: base fp32, curn bf16-packed, |e| partials ----------------
__global__ void err_kernel(const void* ysoft, const int* flags, const int* __restrict__ label,
                           const float* __restrict__ mask01, const float* __restrict__ norm,
                           float* __restrict__ base, unsigned* __restrict__ curn,
                           float* __restrict__ err_part) {
    int i4 = blockIdx.x * 256 + threadIdx.x;     // float4 index
    int node = i4 >> 4;
    int isbf = flags[0];
    float m = mask01[node];
    int lab = label[node];
    float nrm = norm[node];
    int c0 = (i4 & 15) * 4;
    float4 e;
    if (isbf) {
        ushort4 u = ((const ushort4*)ysoft)[i4];
        e.x = __uint_as_float((unsigned)u.x << 16);
        e.y = __uint_as_float((unsigned)u.y << 16);
        e.z = __uint_as_float((unsigned)u.z << 16);
        e.w = __uint_as_float((unsigned)u.w << 16);
    } else {
        e = ((const float4*)ysoft)[i4];
    }
    e.x = (m != 0.f) ? ((c0 + 0 == lab) ? 1.f : 0.f) - e.x : 0.f;
    e.y = (m != 0.f) ? ((c0 + 1 == lab) ? 1.f : 0.f) - e.y : 0.f;
    e.z = (m != 0.f) ? ((c0 + 2 == lab) ? 1.f : 0.f) - e.z : 0.f;
    e.w = (m != 0.f) ? ((c0 + 3 == lab) ? 1.f : 0.f) - e.w : 0.f;
    ((float4*)base)[i4] = e;
    ((uint2*)curn)[i4] = make_uint2(pack_bf16(e.x * nrm, e.y * nrm),
                                    pack_bf16(e.z * nrm, e.w * nrm));
    float a = fabsf(e.x) + fabsf(e.y) + fabsf(e.z) + fabsf(e.w);
    a = wave_sum(a);
    __shared__ float sm[4];
    if ((threadIdx.x & 63) == 0) sm[threadIdx.x >> 6] = a;
    __syncthreads();
    if (threadIdx.x == 0) err_part[blockIdx.x] = sm[0] + sm[1] + sm[2] + sm[3];
}

// ---------------- single-block reduce: scal[0]=numel, scal[1]=sum|err| ----------------
__global__ void reduce_kernel(const float* __restrict__ mask01,
                              const float* __restrict__ err_part, float* __restrict__ scal) {
    int t = threadIdx.x;
    float s0 = 0.f, s1 = 0.f;
    for (int i = t; i < NN; i += 1024) s0 += mask01[i];
    for (int i = t; i < ERR_BLOCKS; i += 1024) s1 += err_part[i];
    __shared__ float a0[1024], a1[1024];
    a0[t] = s0; a1[t] = s1; __syncthreads();
    for (int s = 512; s > 0; s >>= 1) {
        if (t < s) { a0[t] += a0[t + s]; a1[t] += a1[t + s]; }
        __syncthreads();
    }
    if (t == 0) { scal[0] = a0[0]; scal[1] = a1[0]; }
}

// ---------------- pull-gather, bf16 state (wave per node; 2 edges per step) ----------------
// mode 0: store pack_bf16(v*nrm) -> next curn
// mode 1: store fp32 v (float2) + rowsum[node]=sum|v|
// mode 3: final -> d_out per dtype flag
__global__ void gather_kernel(const int* __restrict__ row_ptr, const int* __restrict__ csr_src,
                              const unsigned* __restrict__ curn, const float* __restrict__ base,
                              const float* __restrict__ norm, void* __restrict__ out,
                              float* __restrict__ rowsum, const int* flags,
                              float alpha, float lo, float hi, int mode) {
    int gt = blockIdx.x * blockDim.x + threadIdx.x;
    int node = gt >> 6, lane = gt & 63;
    if (node >= NN) return;
    int hl = lane & 31;          // half-lane: class pair index
    int half = lane >> 5;        // 0 -> even edge, 1 -> odd edge
    int beg = row_ptr[node], end = row_ptr[node + 1];
    float acc0 = 0.f, acc1 = 0.f, acc2 = 0.f, acc3 = 0.f;
    for (int eb = beg; eb < end; eb += 64) {
        int ne = end - eb; if (ne > 64) ne = 64;
        int sv = (eb + lane < end) ? csr_src[eb + lane] : 0;
        int j = 0;
        for (; j + 7 < ne; j += 8) {
            int sA = __shfl(sv, j + 0 + half, 64);
            int sB = __shfl(sv, j + 2 + half, 64);
            int sC = __shfl(sv, j + 4 + half, 64);
            int sD = __shfl(sv, j + 6 + half, 64);
            unsigned wA = curn[(long)sA * 32 + hl];
            unsigned wB = curn[(long)sB * 32 + hl];
            unsigned wC = curn[(long)sC * 32 + hl];
            unsigned wD = curn[(long)sD * 32 + hl];
            acc0 += __uint_as_float(wA << 16) + __uint_as_float(wC << 16);
            acc1 += __uint_as_float(wA & 0xFFFF0000u) + __uint_as_float(wC & 0xFFFF0000u);
            acc2 += __uint_as_float(wB << 16) + __uint_as_float(wD << 16);
            acc3 += __uint_as_float(wB & 0xFFFF0000u) + __uint_as_float(wD & 0xFFFF0000u);
        }
        for (; j < ne; j += 2) {
            int jj = j + half;
            float wt = (jj < ne) ? 1.f : 0.f;
            int s = __shfl(sv, (jj < ne) ? jj : j, 64);
            unsigned w = curn[(long)s * 32 + hl];
            acc0 += wt * __uint_as_float(w << 16);
            acc1 += wt * __uint_as_float(w & 0xFFFF0000u);
        }
    }
    acc0 += acc2; acc1 += acc3;
    acc0 += __shfl_xor(acc0, 32, 64);
    acc1 += __shfl_xor(acc1, 32, 64);

    float nrm = norm[node];
    long i2 = (long)node * 32 + hl;
    float2 b2 = ((const float2*)base)[i2];
    float v0 = (1.f - alpha) * b2.x + alpha * nrm * acc0;
    float v1 = (1.f - alpha) * b2.y + alpha * nrm * acc1;
    v0 = v0 < lo ? lo : (v0 > hi ? hi : v0);
    v1 = v1 < lo ? lo : (v1 > hi ? hi : v1);

    if (mode == 1) {
        float contrib = (lane < 32) ? (fabsf(v0) + fabsf(v1)) : 0.f;
        float rs = wave_sum(contrib);
        if (lane == 0) rowsum[node] = rs;
        if (lane < 32) ((float2*)out)[i2] = make_float2(v0, v1);
    } else if (mode == 0) {
        if (lane < 32) ((unsigned*)out)[i2] = pack_bf16(v0 * nrm, v1 * nrm);
    } else {
        if (lane < 32) {
            if (flags[0]) ((unsigned*)out)[i2] = pack_bf16(v0, v1);
            else          ((float2*)out)[i2] = make_float2(v0, v1);
        }
    }
}

// ---------------- y0 (fused scale): base=y0 fp32, curn=bf16(y0*norm) ----------------
__global__ void y0_kernel(const void* ysoft, const int* flags, const int* __restrict__ label,
                          const float* __restrict__ mask01, const float* __restrict__ rowsum,
                          const float* __restrict__ scal,
                          const float* __restrict__ norm, const float* __restrict__ smoothed,
                          float* __restrict__ base, unsigned* __restrict__ curn) {
    int i4 = blockIdx.x * 256 + threadIdx.x;
    int node = i4 >> 4;
    int isbf = flags[0];
    float m = mask01[node];
    int lab = label[node];
    float nrm = norm[node];
    float sigma = scal[1] / scal[0];
    float sc = sigma / rowsum[node];
    if (isinf(sc) || sc > 1000.f) sc = 1.f;  // NaN falls through (matches ref)
    int c0 = (i4 & 15) * 4;
    float4 ys;
    if (isbf) {
        ushort4 u = ((const ushort4*)ysoft)[i4];
        ys.x = __uint_as_float((unsigned)u.x << 16);
        ys.y = __uint_as_float((unsigned)u.y << 16);
        ys.z = __uint_as_float((unsigned)u.z << 16);
        ys.w = __uint_as_float((unsigned)u.w << 16);
    } else {
        ys = ((const float4*)ysoft)[i4];
    }
    float4 sm = ((const float4*)smoothed)[i4];
    float rx = ys.x + sc * sm.x; if (isnan(rx)) rx = ys.x;
    float ry = ys.y + sc * sm.y; if (isnan(ry)) ry = ys.y;
    float rz = ys.z + sc * sm.z; if (isnan(rz)) rz = ys.z;
    float rw = ys.w + sc * sm.w; if (isnan(rw)) rw = ys.w;
    float4 y;
    y.x = (m != 0.f) ? ((c0 + 0 == lab) ? 1.f : 0.f) : rx;
    y.y = (m != 0.f) ? ((c0 + 1 == lab) ? 1.f : 0.f) : ry;
    y.z = (m != 0.f) ? ((c0 + 2 == lab) ? 1.f : 0.f) : rz;
    y.w = (m != 0.f) ? ((c0 + 3 == lab) ? 1.f : 0.f) : rw;
    ((float4*)base)[i4] = y;
    ((uint2*)curn)[i4] = make_uint2(pack_bf16(y.x * nrm, y.y * nrm),
                                    pack_bf16(y.z * nrm, y.w * nrm));
}

extern "C" void kernel_launch(void* const* d_in, const int* in_sizes, int n_in,
                              void* d_out, int out_size, void* d_ws, size_t ws_size,
                              hipStream_t stream) {
    const void* ysoft = d_in[0];
    const void* ytrue = d_in[1];
    const int* src = (const int*)d_in[2];
    const int* dst = (const int*)d_in[3];
    const void* mask = d_in[4];

    char* ws = (char*)d_ws;
    // ---- zeroed region [0, 16384) ----
    int*   flags       = (int*)ws;
    float* scal        = (float*)(ws + 64);
    int*   bucket_tot  = (int*)(ws + 4096);          // NB ints (zeroed)
    size_t ZERO_BYTES  = 16384;
    int*   bucket_base = (int*)(ws + 16384);         // NB+1 ints (written by bscan)
    int*   bucket_fill = (int*)(ws + 20480);         // NB+1 ints (written by bscan)
    float* err_part    = (float*)(ws + 24576);       // ERR_BLOCKS floats (25 KB)

    size_t off = 24576 + (size_t)ERR_BLOCKS * 4;
    off = (off + 255) & ~(size_t)255;
    int*   label   = (int*)(ws + off);   off += (size_t)NN * 4;
    float* mask01  = (float*)(ws + off); off += (size_t)NN * 4;
    float* norm    = (float*)(ws + off); off += (size_t)NN * 4;
    float* rowsum  = (float*)(ws + off); off += (size_t)NN * 4;
    int*   row_ptr = (int*)(ws + off);   off += (size_t)(NN + 1) * 4;
    off = (off + 255) & ~(size_t)255;
    int*   csr_src = (int*)(ws + off);   off += (size_t)EE * 4;
    off = (off + 255) & ~(size_t)255;
    float*    base     = (float*)(ws + off);    off += (size_t)NC * 4;
    float*    smoothed = (float*)(ws + off);    off += (size_t)NC * 4;
    unsigned* bufA     = (unsigned*)(ws + off); off += (size_t)NC * 2;
    unsigned* bufB     = (unsigned*)(ws + off); off += (size_t)NC * 2;
    // tmp pair buffer aliases base (dead before err_kernel writes base): EE*8 == NC*4
    uint2* tmp = (uint2*)base;

    hipMemsetAsync(ws, 0, ZERO_BYTES, stream);

    detect_kernel<<<1, 256, 0, stream>>>(ytrue, mask, flags);
    prep_kernel<<<(NN * 64 + 255) / 256, 256, 0, stream>>>(ytrue, mask, flags, label, mask01);
    histA_kernel<<<NTILE, 256, 0, stream>>>(dst, bucket_tot);
    bscan_kernel<<<1, 512, 0, stream>>>(bucket_tot, bucket_base, bucket_fill);
    binA_kernel<<<NTILE, 512, 0, stream>>>(src, dst, bucket_fill, tmp);
    csrB_kernel<<<NB, 256, 0, stream>>>(tmp, bucket_base, row_ptr, norm, csr_src);
    err_kernel<<<ERR_BLOCKS, 256, 0, stream>>>(ysoft, flags, label, mask01, norm, base, bufA, err_part);
    reduce_kernel<<<1, 1024, 0, stream>>>(mask01, err_part, scal);

    const int gather_blocks = (NN * 64 + 255) / 256;

    // ---- correct phase: 10 layers, alpha=0.979, clip [-1,1]
    unsigned* cur = bufA; unsigned* nxt = bufB;
    for (int l = 0; l < 10; l++) {
        int mode = (l < 9) ? 0 : 1;
        void* o = (l < 9) ? (void*)nxt : (void*)smoothed;
        gather_kernel<<<gather_blocks, 256, 0, stream>>>(row_ptr, csr_src, cur, base, norm, o,
                                                         rowsum, flags, 0.979f, -1.f, 1.f, mode);
        unsigned* t = cur; cur = nxt; nxt = t;
    }

    y0_kernel<<<ERR_BLOCKS, 256, 0, stream>>>(ysoft, flags, label, mask01, rowsum, scal, norm,
                                              smoothed, base, bufA);

    // ---- smooth phase: 10 layers, alpha=0.756, clip [0,1]; last writes d_out
    cur = bufA; nxt = bufB;
    for (int l = 0; l < 10; l++) {
        int mode = (l < 9) ? 0 : 3;
        void* o = (l < 9) ? (void*)nxt : (void*)d_out;
        gather_kernel<<<gather_blocks, 256, 0, stream>>>(row_ptr, csr_src, cur, base, norm, o,
                                                         rowsum, flags, 0.756f, 0.f, 1.f, mode);
        unsigned* t = cur; cur = nxt; nxt = t;
    }
}

// Round 7
// 1453.462 us; speedup vs baseline: 2.6969x; 1.0304x over previous
//
#include <hip/hip_runtime.h>
#include <hip/hip_bf16.h>

#define NN 100000
#define EE 3200000
#define CC 64
#define NC (NN*CC)
#define ERR_BLOCKS 6250        // NC/4/256
#define NB 391                 // buckets = dst>>8, ceil(NN/256)
#define TILE 8192              // edges per binA block
#define NTILE 391              // ceil(EE/TILE)

// ---------------- helpers ----------------
__device__ __forceinline__ float ldf(const void* p, long i, int isbf) {
    if (isbf) {
        unsigned int u = ((const unsigned short*)p)[i];
        return __uint_as_float(u << 16);
    }
    return ((const float*)p)[i];
}

__device__ __forceinline__ float wave_sum(float a) {
    for (int m = 1; m < 64; m <<= 1) a += __shfl_xor(a, m, 64);
    return a;
}

// round-to-nearest-even bf16 pack of (a -> low16, b -> high16)
__device__ __forceinline__ unsigned pack_bf16(float a, float b) {
    unsigned ua = __float_as_uint(a); ua = (ua + 0x7FFFu + ((ua >> 16) & 1u)) >> 16;
    unsigned ub = __float_as_uint(b); ub = (ub + 0x7FFFu + ((ub >> 16) & 1u)) >> 16;
    return ua | (ub << 16);
}

// ---------------- detection (1 block, sampled) ----------------
__global__ void detect_kernel(const void* ytrue, const void* mask, int* flags) {
    int t = threadIdx.x;
    const unsigned int* w = (const unsigned int*)ytrue;
    int nb = 0, nm = 0;
    for (int i = t; i < 16384; i += 256)
        if ((w[i] & 0xFFFFu) == 0x3F80u) nb = 1;   // bf16 1.0 at even class
    const unsigned char* mb = (const unsigned char*)mask;
    for (int i = t; i < 4096; i += 256)
        if ((i & 3) != 0 && mb[i] != 0) nm = 1;
    if (nb) atomicOr(&flags[0], 1);
    if (nm) atomicOr(&flags[1], 1);
}

// ---------------- prep: wave per node; label via ballot ----------------
__global__ void prep_kernel(const void* ytrue, const void* mask, const int* flags,
                            int* __restrict__ label, float* __restrict__ mask01) {
    int gt = blockIdx.x * blockDim.x + threadIdx.x;
    int node = gt >> 6, lane = gt & 63;
    if (node >= NN) return;
    int isbf = flags[0];
    float tv = ldf(ytrue, (long)node * CC + lane, isbf);
    unsigned long long b = __ballot(tv > 0.5f);
    if (lane == 0) {
        label[node] = (b == 0ull) ? 0 : (__ffsll((long long)b) - 1);
        int mv = flags[1] ? (int)((const unsigned char*)mask)[node] : ((const int*)mask)[node];
        mask01[node] = mv ? 1.f : 0.f;
    }
}

// ---------------- bucket histogram (LDS-aggregated) ----------------
__global__ void histA_kernel(const int* __restrict__ dst, int* __restrict__ bucket_tot) {
    __shared__ int hist[NB];
    int t = threadIdx.x;
    for (int b = t; b < NB; b += 256) hist[b] = 0;
    __syncthreads();
    int e0 = blockIdx.x * TILE;
    int n = EE - e0; if (n > TILE) n = TILE;
    for (int k = t; k < n; k += 256)
        atomicAdd(&hist[dst[e0 + k] >> 8], 1);
    __syncthreads();
    for (int b = t; b < NB; b += 256)
        if (hist[b]) atomicAdd(&bucket_tot[b], hist[b]);
}

// ---------------- scan bucket totals -> bucket_base / bucket_fill ----------------
__global__ void bscan_kernel(const int* __restrict__ bucket_tot,
                             int* __restrict__ bucket_base, int* __restrict__ bucket_fill) {
    int t = threadIdx.x;
    __shared__ int sm[512];
    int v = (t < NB) ? bucket_tot[t] : 0;
    sm[t] = v; __syncthreads();
    for (int off = 1; off < 512; off <<= 1) {
        int x = (t >= off) ? sm[t - off] : 0;
        __syncthreads();
        sm[t] += x;
        __syncthreads();
    }
    int ex = sm[t] - v;
    if (t <= NB) { bucket_base[t] = ex; bucket_fill[t] = ex; }
}

// ---------------- binning: LDS-stage a tile sorted by bucket, write runs ----------------
__global__ void __launch_bounds__(512)
binA_kernel(const int* __restrict__ src, const int* __restrict__ dst,
            int* __restrict__ bucket_fill, uint2* __restrict__ tmp) {
    __shared__ uint2 stage[TILE];
    __shared__ int hist[512], hofs[512], curL[512], gbase[512];
    __shared__ int sm[512];
    int t = threadIdx.x;
    int e0 = blockIdx.x * TILE;
    int n = EE - e0; if (n > TILE) n = TILE;

    hist[t] = 0;
    __syncthreads();
    for (int k = t; k < n; k += 512)
        atomicAdd(&hist[dst[e0 + k] >> 8], 1);
    __syncthreads();
    int v = hist[t];
    sm[t] = v; __syncthreads();
    for (int off = 1; off < 512; off <<= 1) {
        int x = (t >= off) ? sm[t - off] : 0;
        __syncthreads();
        sm[t] += x;
        __syncthreads();
    }
    hofs[t] = sm[t] - v;
    curL[t] = sm[t] - v;
    __syncthreads();
    for (int k = t; k < n; k += 512) {
        int s = src[e0 + k], d = dst[e0 + k];
        int b = d >> 8;
        int p = atomicAdd(&curL[b], 1);
        stage[p] = make_uint2((unsigned)s, (unsigned)d);
    }
    if (t < NB) {
        int c = hist[t];
        gbase[t] = c ? atomicAdd(&bucket_fill[t], c) : 0;
    }
    __syncthreads();
    for (int k = t; k < n; k += 512) {
        uint2 pr = stage[k];
        int b = (int)(pr.y >> 8);
        tmp[gbase[b] + (k - hofs[b])] = pr;
    }
}

// ---------------- per-bucket exact counting sort; emits row_ptr, norm, csr_src ----------
__global__ void __launch_bounds__(256)
csrB_kernel(const uint2* __restrict__ tmp, const int* __restrict__ bucket_base,
            int* __restrict__ row_ptr, float* __restrict__ norm, int* __restrict__ csr_src) {
    __shared__ int deg[256], cur[256], sm[256];
    int t = threadIdx.x, b = blockIdx.x;
    int ebeg = bucket_base[b], eend = bucket_base[b + 1];
    deg[t] = 0;
    __syncthreads();
    for (int i = ebeg + t; i < eend; i += 256)
        atomicAdd(&deg[tmp[i].y & 255u], 1);
    __syncthreads();
    int v = deg[t];
    sm[t] = v; __syncthreads();
    for (int off = 1; off < 256; off <<= 1) {
        int x = (t >= off) ? sm[t - off] : 0;
        __syncthreads();
        sm[t] += x;
        __syncthreads();
    }
    int lofs = sm[t] - v;
    int node = b * 256 + t;
    if (node < NN) {
        row_ptr[node] = ebeg + lofs;
        int d = v; if (d < 1) d = 1;
        norm[node] = rsqrtf((float)d);
    }
    if (b == NB - 1 && t == 0) row_ptr[NN] = EE;
    cur[t] = lofs;
    __syncthreads();
    for (int i = ebeg + t; i < eend; i += 256) {
        uint2 pr = tmp[i];
        int p = atomicAdd(&cur[pr.y & 255u], 1);
        csr_src[ebeg + p] = (int)pr.x;
    }
}

// ---------------- initial error: base fp32, curn bf16-packed, |e| partials ----------------
__global__ void err_kernel(const void* ysoft, const int* flags, const int* __restrict__ label,
                           const float* __restrict__ mask01, const float* __restrict__ norm,
                           float* __restrict__ base, unsigned* __restrict__ curn,
                           float* __restrict__ err_part) {
    int i4 = blockIdx.x * 256 + threadIdx.x;     // float4 index
    int node = i4 >> 4;
    int isbf = flags[0];
    float m = mask01[node];
    int lab = label[node];
    float nrm = norm[node];
    int c0 = (i4 & 15) * 4;
    float4 e;
    if (isbf) {
        ushort4 u = ((const ushort4*)ysoft)[i4];
        e.x = __uint_as_float((unsigned)u.x << 16);
        e.y = __uint_as_float((unsigned)u.y << 16);
        e.z = __uint_as_float((unsigned)u.z << 16);
        e.w = __uint_as_float((unsigned)u.w << 16);
    } else {
        e = ((const float4*)ysoft)[i4];
    }
    e.x = (m != 0.f) ? ((c0 + 0 == lab) ? 1.f : 0.f) - e.x : 0.f;
    e.y = (m != 0.f) ? ((c0 + 1 == lab) ? 1.f : 0.f) - e.y : 0.f;
    e.z = (m != 0.f) ? ((c0 + 2 == lab) ? 1.f : 0.f) - e.z : 0.f;
    e.w = (m != 0.f) ? ((c0 + 3 == lab) ? 1.f : 0.f) - e.w : 0.f;
    ((float4*)base)[i4] = e;
    ((uint2*)curn)[i4] = make_uint2(pack_bf16(e.x * nrm, e.y * nrm),
                                    pack_bf16(e.z * nrm, e.w * nrm));
    float a = fabsf(e.x) + fabsf(e.y) + fabsf(e.z) + fabsf(e.w);
    a = wave_sum(a);
    __shared__ float sm[4];
    if ((threadIdx.x & 63) == 0) sm[threadIdx.x >> 6] = a;
    __syncthreads();
    if (threadIdx.x == 0) err_part[blockIdx.x] = sm[0] + sm[1] + sm[2] + sm[3];
}

// ---------------- single-block reduce: scal[0]=numel, scal[1]=sum|err| ----------------
__global__ void reduce_kernel(const float* __restrict__ mask01,
                              const float* __restrict__ err_part, float* __restrict__ scal) {
    int t = threadIdx.x;
    float s0 = 0.f, s1 = 0.f;
    for (int i = t; i < NN; i += 1024) s0 += mask01[i];
    for (int i = t; i < ERR_BLOCKS; i += 1024) s1 += err_part[i];
    __shared__ float a0[1024], a1[1024];
    a0[t] = s0; a1[t] = s1; __syncthreads();
    for (int s = 512; s > 0; s >>= 1) {
        if (t < s) { a0[t] += a0[t + s]; a1[t] += a1[t + s]; }
        __syncthreads();
    }
    if (t == 0) { scal[0] = a0[0]; scal[1] = a1[0]; }
}

// ---------------- pull-gather, bf16 state, deep-MLP (16 edges / 8 loads per step) -------
// mode 0: store pack_bf16(v*nrm) -> next curn
// mode 1: store fp32 v (float2) + rowsum[node]=sum|v|
// mode 3: final -> d_out per dtype flag
__global__ void gather_kernel(const int* __restrict__ row_ptr, const int* __restrict__ csr_src,
                              const unsigned* __restrict__ curn, const float* __restrict__ base,
                              const float* __restrict__ norm, void* __restrict__ out,
                              float* __restrict__ rowsum, const int* flags,
                              float alpha, float lo, float hi, int mode) {
    int gt = blockIdx.x * blockDim.x + threadIdx.x;
    int node = gt >> 6, lane = gt & 63;
    if (node >= NN) return;
    int hl = lane & 31;          // half-lane: class pair index
    int half = lane >> 5;        // 0 -> even edge, 1 -> odd edge
    int beg = row_ptr[node], end = row_ptr[node + 1];

    // hoist epilogue loads ahead of the gather loop (overlap latency)
    float nrm = norm[node];
    long i2 = (long)node * 32 + hl;
    float2 b2;
    {
        const float* bp = base + i2 * 2;     // streamed once per layer: nontemporal
        b2.x = __builtin_nontemporal_load(bp);
        b2.y = __builtin_nontemporal_load(bp + 1);
    }

    float acc0 = 0.f, acc1 = 0.f, acc2 = 0.f, acc3 = 0.f;
    for (int eb = beg; eb < end; eb += 64) {
        int ne = end - eb; if (ne > 64) ne = 64;
        int sv = (eb + lane < end) ? __builtin_nontemporal_load(csr_src + eb + lane) : 0;
        int j = 0;
        // 16 edges per step: 8 independent row-loads in flight per lane
        for (; j + 15 < ne; j += 16) {
            int s0 = __shfl(sv, j + 0  + half, 64);
            int s1 = __shfl(sv, j + 2  + half, 64);
            int s2 = __shfl(sv, j + 4  + half, 64);
            int s3 = __shfl(sv, j + 6  + half, 64);
            int s4 = __shfl(sv, j + 8  + half, 64);
            int s5 = __shfl(sv, j + 10 + half, 64);
            int s6 = __shfl(sv, j + 12 + half, 64);
            int s7 = __shfl(sv, j + 14 + half, 64);
            unsigned w0 = curn[(long)s0 * 32 + hl];
            unsigned w1 = curn[(long)s1 * 32 + hl];
            unsigned w2 = curn[(long)s2 * 32 + hl];
            unsigned w3 = curn[(long)s3 * 32 + hl];
            unsigned w4 = curn[(long)s4 * 32 + hl];
            unsigned w5 = curn[(long)s5 * 32 + hl];
            unsigned w6 = curn[(long)s6 * 32 + hl];
            unsigned w7 = curn[(long)s7 * 32 + hl];
            acc0 += __uint_as_float(w0 << 16) + __uint_as_float(w2 << 16)
                  + __uint_as_float(w4 << 16) + __uint_as_float(w6 << 16);
            acc1 += __uint_as_float(w0 & 0xFFFF0000u) + __uint_as_float(w2 & 0xFFFF0000u)
                  + __uint_as_float(w4 & 0xFFFF0000u) + __uint_as_float(w6 & 0xFFFF0000u);
            acc2 += __uint_as_float(w1 << 16) + __uint_as_float(w3 << 16)
                  + __uint_as_float(w5 << 16) + __uint_as_float(w7 << 16);
            acc3 += __uint_as_float(w1 & 0xFFFF0000u) + __uint_as_float(w3 & 0xFFFF0000u)
                  + __uint_as_float(w5 & 0xFFFF0000u) + __uint_as_float(w7 & 0xFFFF0000u);
        }
        for (; j + 7 < ne; j += 8) {
            int s0 = __shfl(sv, j + 0 + half, 64);
            int s1 = __shfl(sv, j + 2 + half, 64);
            int s2 = __shfl(sv, j + 4 + half, 64);
            int s3 = __shfl(sv, j + 6 + half, 64);
            unsigned w0 = curn[(long)s0 * 32 + hl];
            unsigned w1 = curn[(long)s1 * 32 + hl];
            unsigned w2 = curn[(long)s2 * 32 + hl];
            unsigned w3 = curn[(long)s3 * 32 + hl];
            acc0 += __uint_as_float(w0 << 16) + __uint_as_float(w2 << 16);
            acc1 += __uint_as_float(w0 & 0xFFFF0000u) + __uint_as_float(w2 & 0xFFFF0000u);
            acc2 += __uint_as_float(w1 << 16) + __uint_as_float(w3 << 16);
            acc3 += __uint_as_float(w1 & 0xFFFF0000u) + __uint_as_float(w3 & 0xFFFF0000u);
        }
        for (; j < ne; j += 2) {
            int jj = j + half;
            float wt = (jj < ne) ? 1.f : 0.f;
            int s = __shfl(sv, (jj < ne) ? jj : j, 64);
            unsigned w = curn[(long)s * 32 + hl];
            acc0 += wt * __uint_as_float(w << 16);
            acc1 += wt * __uint_as_float(w & 0xFFFF0000u);
        }
    }
    acc0 += acc2; acc1 += acc3;
    acc0 += __shfl_xor(acc0, 32, 64);
    acc1 += __shfl_xor(acc1, 32, 64);

    float v0 = (1.f - alpha) * b2.x + alpha * nrm * acc0;
    float v1 = (1.f - alpha) * b2.y + alpha * nrm * acc1;
    v0 = v0 < lo ? lo : (v0 > hi ? hi : v0);
    v1 = v1 < lo ? lo : (v1 > hi ? hi : v1);

    if (mode == 1) {
        float contrib = (lane < 32) ? (fabsf(v0) + fabsf(v1)) : 0.f;
        float rs = wave_sum(contrib);
        if (lane == 0) rowsum[node] = rs;
        if (lane < 32) {
            float* op = (float*)out + i2 * 2;
            __builtin_nontemporal_store(v0, op);
            __builtin_nontemporal_store(v1, op + 1);
        }
    } else if (mode == 0) {
        if (lane < 32)
            __builtin_nontemporal_store(pack_bf16(v0 * nrm, v1 * nrm), (unsigned*)out + i2);
    } else {
        if (lane < 32) {
            if (flags[0]) __builtin_nontemporal_store(pack_bf16(v0, v1), (unsigned*)out + i2);
            else {
                float* op = (float*)out + i2 * 2;
                __builtin_nontemporal_store(v0, op);
                __builtin_nontemporal_store(v1, op + 1);
            }
        }
    }
}

// ---------------- y0 (fused scale): base=y0 fp32, curn=bf16(y0*norm) ----------------
__global__ void y0_kernel(const void* ysoft, const int* flags, const int* __restrict__ label,
                          const float* __restrict__ mask01, const float* __restrict__ rowsum,
                          const float* __restrict__ scal,
                          const float* __restrict__ norm, const float* __restrict__ smoothed,
                          float* __restrict__ base, unsigned* __restrict__ curn) {
    int i4 = blockIdx.x * 256 + threadIdx.x;
    int node = i4 >> 4;
    int isbf = flags[0];
    float m = mask01[node];
    int lab = label[node];
    float nrm = norm[node];
    float sigma = scal[1] / scal[0];
    float sc = sigma / rowsum[node];
    if (isinf(sc) || sc > 1000.f) sc = 1.f;  // NaN falls through (matches ref)
    int c0 = (i4 & 15) * 4;
    float4 ys;
    if (isbf) {
        ushort4 u = ((const ushort4*)ysoft)[i4];
        ys.x = __uint_as_float((unsigned)u.x << 16);
        ys.y = __uint_as_float((unsigned)u.y << 16);
        ys.z = __uint_as_float((unsigned)u.z << 16);
        ys.w = __uint_as_float((unsigned)u.w << 16);
    } else {
        ys = ((const float4*)ysoft)[i4];
    }
    float4 sm = ((const float4*)smoothed)[i4];
    float rx = ys.x + sc * sm.x; if (isnan(rx)) rx = ys.x;
    float ry = ys.y + sc * sm.y; if (isnan(ry)) ry = ys.y;
    float rz = ys.z + sc * sm.z; if (isnan(rz)) rz = ys.z;
    float rw = ys.w + sc * sm.w; if (isnan(rw)) rw = ys.w;
    float4 y;
    y.x = (m != 0.f) ? ((c0 + 0 == lab) ? 1.f : 0.f) : rx;
    y.y = (m != 0.f) ? ((c0 + 1 == lab) ? 1.f : 0.f) : ry;
    y.z = (m != 0.f) ? ((c0 + 2 == lab) ? 1.f : 0.f) : rz;
    y.w = (m != 0.f) ? ((c0 + 3 == lab) ? 1.f : 0.f) : rw;
    ((float4*)base)[i4] = y;
    ((uint2*)curn)[i4] = make_uint2(pack_bf16(y.x * nrm, y.y * nrm),
                                    pack_bf16(y.z * nrm, y.w * nrm));
}

extern "C" void kernel_launch(void* const* d_in, const int* in_sizes, int n_in,
                              void* d_out, int out_size, void* d_ws, size_t ws_size,
                              hipStream_t stream) {
    const void* ysoft = d_in[0];
    const void* ytrue = d_in[1];
    const int* src = (const int*)d_in[2];
    const int* dst = (const int*)d_in[3];
    const void* mask = d_in[4];

    char* ws = (char*)d_ws;
    // ---- zeroed region [0, 16384) ----
    int*   flags       = (int*)ws;
    float* scal        = (float*)(ws + 64);
    int*   bucket_tot  = (int*)(ws + 4096);          // NB ints (zeroed)
    size_t ZERO_BYTES  = 16384;
    int*   bucket_base = (int*)(ws + 16384);         // NB+1 ints (written by bscan)
    int*   bucket_fill = (int*)(ws + 20480);         // NB+1 ints (written by bscan)
    float* err_part    = (float*)(ws + 24576);       // ERR_BLOCKS floats (25 KB)

    size_t off = 24576 + (size_t)ERR_BLOCKS * 4;
    off = (off + 255) & ~(size_t)255;
    int*   label   = (int*)(ws + off);   off += (size_t)NN * 4;
    float* mask01  = (float*)(ws + off); off += (size_t)NN * 4;
    float* norm    = (float*)(ws + off); off += (size_t)NN * 4;
    float* rowsum  = (float*)(ws + off); off += (size_t)NN * 4;
    int*   row_ptr = (int*)(ws + off);   off += (size_t)(NN + 1) * 4;
    off = (off + 255) & ~(size_t)255;
    int*   csr_src = (int*)(ws + off);   off += (size_t)EE * 4;
    off = (off + 255) & ~(size_t)255;
    float*    base     = (float*)(ws + off);    off += (size_t)NC * 4;
    float*    smoothed = (float*)(ws + off);    off += (size_t)NC * 4;
    unsigned* bufA     = (unsigned*)(ws + off); off += (size_t)NC * 2;
    unsigned* bufB     = (unsigned*)(ws + off); off += (size_t)NC * 2;
    // tmp pair buffer aliases base (dead before err_kernel writes base): EE*8 == NC*4
    uint2* tmp = (uint2*)base;

    hipMemsetAsync(ws, 0, ZERO_BYTES, stream);

    detect_kernel<<<1, 256, 0, stream>>>(ytrue, mask, flags);
    prep_kernel<<<(NN * 64 + 255) / 256, 256, 0, stream>>>(ytrue, mask, flags, label, mask01);
    histA_kernel<<<NTILE, 256, 0, stream>>>(dst, bucket_tot);
    bscan_kernel<<<1, 512, 0, stream>>>(bucket_tot, bucket_base, bucket_fill);
    binA_kernel<<<NTILE, 512, 0, stream>>>(src, dst, bucket_fill, tmp);
    csrB_kernel<<<NB, 256, 0, stream>>>(tmp, bucket_base, row_ptr, norm, csr_src);
    err_kernel<<<ERR_BLOCKS, 256, 0, stream>>>(ysoft, flags, label, mask01, norm, base, bufA, err_part);
    reduce_kernel<<<1, 1024, 0, stream>>>(mask01, err_part, scal);

    const int gather_blocks = (NN * 64 + 255) / 256;

    // ---- correct phase: 10 layers, alpha=0.979, clip [-1,1]
    unsigned* cur = bufA; unsigned* nxt = bufB;
    for (int l = 0; l < 10; l++) {
        int mode = (l < 9) ? 0 : 1;
        void* o = (l < 9) ? (void*)nxt : (void*)smoothed;
        gather_kernel<<<gather_blocks, 256, 0, stream>>>(row_ptr, csr_src, cur, base, norm, o,
                                                         rowsum, flags, 0.979f, -1.f, 1.f, mode);
        unsigned* t = cur; cur = nxt; nxt = t;
    }

    y0_kernel<<<ERR_BLOCKS, 256, 0, stream>>>(ysoft, flags, label, mask01, rowsum, scal, norm,
                                              smoothed, base, bufA);

    // ---- smooth phase: 10 layers, alpha=0.756, clip [0,1]; last writes d_out
    cur = bufA; nxt = bufB;
    for (int l = 0; l < 10; l++) {
        int mode = (l < 9) ? 0 : 3;
        void* o = (l < 9) ? (void*)nxt : (void*)d_out;
        gather_kernel<<<gather_blocks, 256, 0, stream>>>(row_ptr, csr_src, cur, base, norm, o,
                                                         rowsum, flags, 0.756f, 0.f, 1.f, mode);
        unsigned* t = cur; cur = nxt; nxt = t;
    }
}